// Round 13
// baseline (132.419 us; speedup 1.0000x reference)
//
#include <hip/hip_runtime.h>
#include <math.h>
#include <stdint.h>

#define NF_     13776
#define R_      128
#define NPIX_   (R_ * R_)
#define CH_     256
#define NSLICE_ 32
#define FPS_    ((NF_ + NSLICE_ - 1) / NSLICE_)
#define NBKT_   256
#define NSEG_   4
#define SEGSZ_  (NF_ / NSEG_)                    // 3444 exactly

typedef unsigned long long u64;
typedef unsigned int u32;

// exact f32 constants matching the JAX reference
#define EYEZ_F     (-2.7320508075688772935f)     // -(1/tan(30deg) + 1)
#define INV_FAR_F  (0.04f)
#define INV_NEAR_F (10.0f)
#define FAR_BITS   0x41C80000u                   // bits of 25.0f
#define HIT_THR_F  ((float)(25.0 * (1.0 - 1e-06)))
#define SENTINEL_  (((u64)FAR_BITS << 32))       // depth=FAR, fid=0
// z-bucket mapping: bucket = min(255, (int)(zeff*32)); BKT_LO(b) <= zmin_eff of all members
#define BKT_SCALE  32.0f
#define BKT_LO(b)  ((float)(b) * (0.03125f * 0.999999f))

static __device__ __forceinline__ float pix_coord(int j) {
    return (2.0f * (float)j + 1.0f - 128.0f) / 128.0f;   // exact in f32
}

static __device__ __forceinline__ void tile_masks(float4 bb, int& xm, int& ym) {
    xm = 0; ym = 0;
    #pragma unroll
    for (int t = 0; t < 8; ++t) {
        float tx0 = pix_coord(t * 16), tx1 = pix_coord(t * 16 + 15);
        if (bb.x <= tx1 && bb.y >= tx0) xm |= 1 << t;
        float ty1 = -pix_coord(t * 16), ty0 = -pix_coord(t * 16 + 15);
        if (bb.z <= ty1 && bb.w >= ty0) ym |= 1 << t;
    }
}

// Conservative: returns true => NO pixel center in [rx0,rx1]x[ry0,ry1] can pass
// the exact per-pixel sign tests s0&&s1. Linear edge fn attains extrema at rect
// corners; margin 1e-4 >> worst-case f32 rounding (~1e-5 at |terms|<=~40).
static __device__ __forceinline__ bool edge_cull(float a, float b, float c, float d,
                                                 float x2, float y2, float dets,
                                                 float rx0, float rx1,
                                                 float ry0, float ry1)
{
#pragma clang fp contract(off)
    float s = (__float_as_uint(dets) >> 31) ? -1.0f : 1.0f;
    float dx0 = rx0 - x2, dx1 = rx1 - x2;
    float dy0 = ry0 - y2, dy1 = ry1 - y2;
    float e0 = s * (a * dx0 + b * dy0);
    float e1 = s * (a * dx0 + b * dy1);
    float e2 = s * (a * dx1 + b * dy0);
    float e3 = s * (a * dx1 + b * dy1);
    if (fmaxf(fmaxf(e0, e1), fmaxf(e2, e3)) < -1e-4f) return true;
    float f0 = s * (c * dx0 + d * dy0);
    float f1 = s * (c * dx0 + d * dy1);
    float f2 = s * (c * dx1 + d * dy0);
    float f3 = s * (c * dx1 + d * dy1);
    return fmaxf(fmaxf(f0, f1), fmaxf(f2, f3)) < -1e-4f;
}

// ---- init: zero (tile,bucket,seg) counters (separate: kpre atomics race otherwise) ----
__global__ __launch_bounds__(256) void kinit(uint4* __restrict__ cnt4)
{
    int p = blockIdx.x * 256 + threadIdx.x;      // 64 blocks x 256 = 16384 uint4
    cnt4[p] = make_uint4(0u, 0u, 0u, 0u);        // == 65536 u32
}

__global__ __launch_bounds__(256) void kinitP(u64* __restrict__ pd64)   // fallback only
{
    int p = blockIdx.x * 256 + threadIdx.x;
    if (p < NPIX_) pd64[p] = SENTINEL_;
}

// ---- preprocess + edge-culled tile mask + fire-and-forget (tile,bkt,seg) count ----
__global__ __launch_bounds__(256) void kpre(const float* __restrict__ verts,
                                            const int* __restrict__ faces,
                                            float4* __restrict__ fq0,
                                            float4* __restrict__ fq1,
                                            float4* __restrict__ fq2,
                                            float4* __restrict__ bbx,
                                            int* __restrict__ cull,
                                            u32* __restrict__ fw,
                                            u64* __restrict__ tmask,
                                            u32* __restrict__ cnt,
                                            int do_count)
{
#pragma clang fp contract(off)
    int f = blockIdx.x * 256 + threadIdx.x;
    if (f >= NF_) return;
    int i0 = faces[3*f+0], i1 = faces[3*f+1], i2 = faces[3*f+2];
    float x0 = verts[3*i0+0], y0 = verts[3*i0+1], z0 = verts[3*i0+2] - EYEZ_F;
    float x1 = verts[3*i1+0], y1 = verts[3*i1+1], z1 = verts[3*i1+2] - EYEZ_F;
    float x2 = verts[3*i2+0], y2 = verts[3*i2+1], z2 = verts[3*i2+2] - EYEZ_F;

    float a = y1 - y2;
    float b = x2 - x1;
    float c = y2 - y0;
    float d = x0 - x2;
    float e = y0 - y2;
    float det = a * d + b * e;                   // no FMA (contract off)
    bool det_ok = fabsf(det) > 1e-10f;
    float dets = det_ok ? det : 1e-10f;
    bool zpos = (z0 > 0.1f) && (z1 > 0.1f) && (z2 > 0.1f);

    // conservative prune bound: any valid candidate's computed depth > zmin_eff (strict)
    float zmin_eff = fminf(z0, fminf(z1, z2)) * 0.99999f;

    float4 bb = make_float4(fminf(x0, fminf(x1, x2)) - 1e-4f,
                            fmaxf(x0, fmaxf(x1, x2)) + 1e-4f,
                            fminf(y0, fminf(y1, y2)) - 1e-4f,
                            fmaxf(y0, fmaxf(y1, y2)) + 1e-4f);
    int ok = (det_ok && zpos) ? 0 : 1;

    fq0[f] = make_float4(a, b, c, d);
    fq1[f] = make_float4(x2, y2, dets, zmin_eff);
    fq2[f] = make_float4(z0, z1, z2, __uint_as_float((u32)f));
    bbx[f] = bb;
    cull[f] = ok;

    u64 tm = 0;
    u32 w = 0;
    if (ok == 0) {
        int xm, ym; tile_masks(bb, xm, ym);
        u32 bkt = (u32)min(255, (int)(zmin_eff * BKT_SCALE));
        w = bkt << 16;
        int seg = f / SEGSZ_;                    // 0..3
        for (int tr = 0; tr < 8; ++tr) if ((ym >> tr) & 1) {
            float ty1 = -pix_coord(tr * 16);         // max y in tile
            float ty0 = -pix_coord(tr * 16 + 15);    // min y in tile
            for (int tc = 0; tc < 8; ++tc) if ((xm >> tc) & 1) {
                float tx0 = pix_coord(tc * 16), tx1 = pix_coord(tc * 16 + 15);
                if (!edge_cull(a, b, c, d, x2, y2, dets, tx0, tx1, ty0, ty1)) {
                    tm |= 1ull << (tr * 8 + tc);
                    if (do_count)   // fire-and-forget (no return -> no round-trip wait)
                        atomicAdd(&cnt[(((tr * 8 + tc) * NBKT_) + bkt) * NSEG_ + seg], 1u);
                }
            }
        }
    }
    fw[f] = w;
    tmask[f] = tm;
}

// ---- binsort: 256 blocks = (tile, seg); 1024-wide prefix + segment scatter ----
__global__ __launch_bounds__(256) void kbinsort2(const u32* __restrict__ fw,
                                                 const u64* __restrict__ tmask,
                                                 const u32* __restrict__ cnt,
                                                 u32* __restrict__ list,
                                                 int* __restrict__ len)
{
    __shared__ u32 pexcl[NBKT_ * NSEG_];         // 1024 exclusive starts
    __shared__ u32 tsum[256];
    __shared__ u32 loff[NBKT_];
    const int b = blockIdx.x;
    const int t = b >> 2, seg = b & 3;
    const int tid = threadIdx.x;

    // bucket-major seg-minor linear order => exclusive prefix yields disjoint
    // (bkt,seg) ranges and a bucket-ascending final list (prune invariant kept)
    uint4 v = ((const uint4*)cnt)[t * NBKT_ + tid];
    u32 qs = v.x + v.y + v.z + v.w;
    tsum[tid] = qs;
    __syncthreads();
    for (int d = 1; d < 256; d <<= 1) {
        u32 add = (tid >= d) ? tsum[tid - d] : 0;
        __syncthreads();
        tsum[tid] += add;
        __syncthreads();
    }
    u32 tbase = tsum[tid] - qs;                  // exclusive thread base
    pexcl[tid * 4 + 0] = tbase;
    pexcl[tid * 4 + 1] = tbase + v.x;
    pexcl[tid * 4 + 2] = tbase + v.x + v.y;
    pexcl[tid * 4 + 3] = tbase + v.x + v.y + v.z;
    if (tid == 255 && seg == 0) len[t] = (int)(tbase + qs);
    __syncthreads();
    loff[tid] = pexcl[tid * 4 + seg];            // bucket tid's start for my segment
    __syncthreads();

    // scatter only my segment's faces, 4-deep prefetch; within-bucket order is
    // arbitrary (safe: packed (depth,fid) u64 argmin is fully order-independent)
    const int f0 = seg * SEGSZ_, f1 = f0 + SEGSZ_;
    for (int base = f0; base < f1; base += 1024) {
        u64 tm[4]; u32 w[4]; int fi[4];
        #pragma unroll
        for (int u = 0; u < 4; ++u) {
            int f = base + u * 256 + tid;
            fi[u] = f;
            bool okf = f < f1;
            tm[u] = okf ? tmask[f] : 0ull;
            w[u]  = okf ? fw[f] : 0u;
        }
        #pragma unroll
        for (int u = 0; u < 4; ++u) {
            if ((tm[u] >> t) & 1ull) {
                u32 bkt = w[u] >> 16;
                u32 slot = atomicAdd(&loff[bkt], 1u);
                list[(size_t)t * NF_ + slot] = (bkt << 16) | (u32)fi[u];
            }
        }
    }
}

// ---- fused scan+finalize: 1024 blocks = (tile, quadrant); sole owner of 64 px ----
// Walks the bucket-ascending list from chunk 0: own best converges on nearest-z
// chunk immediately, so the __syncthreads_and break needs no cross-block state.
__global__ __launch_bounds__(256) void kscan6(const float4* __restrict__ fq0,
                                              const float4* __restrict__ fq1,
                                              const float4* __restrict__ fq2,
                                              const int* __restrict__ len,
                                              const u32* __restrict__ list,
                                              const float* __restrict__ tex,
                                              float* __restrict__ out)
{
#pragma clang fp contract(off)
    __shared__ float4 c0s[CH_], c1s[CH_], c2s[CH_];
    __shared__ u64 pb[256];
    const int bx = blockIdx.x;
    const int t = bx >> 2, q = bx & 3;               // tile, 8x8-px quadrant
    const int tid = threadIdx.x;
    const int g = tid >> 6, l = tid & 63;            // candidate-group (wave), pixel
    const int ir0 = (t >> 3) * 16 + (q >> 1) * 8;    // quadrant row base
    const int jc0 = (t & 7) * 16 + (q & 1) * 8;      // quadrant col base
    const int ii = ir0 + (l >> 3);
    const int jj = jc0 + (l & 7);
    const int p  = ii * R_ + jj;
    const float px = pix_coord(jj);
    const float py = -pix_coord(ii);
    const int len_t = len[t];
    const u32* lp = list + (size_t)t * NF_;
    const float qx0 = pix_coord(jc0), qx1 = pix_coord(jc0 + 7);
    const float qy0 = -pix_coord(ir0 + 7), qy1 = -pix_coord(ir0);

    u64 best = SENTINEL_ | 0xFFFFFFFFull;            // (FAR, miss)
    float bestd = 25.0f;

    for (int base = 0; base < len_t; base += CH_) {
        // chunk prune: list bucket-ascending; BKT_LO lower-bounds every zmin_eff
        // in/after this chunk. All 256 threads agree => break is safe & exact.
        float blo = BKT_LO(lp[base] >> 16);
        if (__syncthreads_and(blo > bestd)) break;

        const int K = min(CH_, len_t - base);
        if (tid < K) {
            int f = (int)(lp[base + tid] & 0xFFFFu);
            float4 a0 = fq0[f];
            float4 a1 = fq1[f];
            // quadrant-level conservative edge cull: mark dead via zmin=+inf so
            // the per-candidate prune skips it (bestd <= 25 < 1e30 always)
            if (edge_cull(a0.x, a0.y, a0.z, a0.w, a1.x, a1.y, a1.z,
                          qx0, qx1, qy0, qy1))
                a1.w = 1e30f;
            c0s[tid] = a0;
            c1s[tid] = a1;
            c2s[tid] = fq2[f];
        }
        __syncthreads();

        // interleaved split: group g takes k = g, g+4, ... (groups sweep z together)
        for (int k = g; k < K; k += 4) {
            float4 q1 = c1s[k];                   // x2,y2,det,zmin_eff (LDS broadcast)
            if (q1.w > bestd) continue;           // strict: preserves exact ties
            float4 q0 = c0s[k];                   // a,b,c,d
            float dx = px - q1.x, dy = py - q1.y;
            float n0 = q0.x * dx + q0.y * dy;
            float n1 = q0.z * dx + q0.w * dy;
            u32 sd = __float_as_uint(q1.z) >> 31;
            bool s0 = (n0 == 0.0f) || ((__float_as_uint(n0) >> 31) == sd);
            bool s1 = (n1 == 0.0f) || ((__float_as_uint(n1) >> 31) == sd);
            if (!(s0 && s1)) continue;
            float w0 = n0 / q1.z;
            float w1 = n1 / q1.z;
            float w2 = 1.0f - w0 - w1;
            if (!(w2 >= 0.0f)) continue;
            float4 q2 = c2s[k];                   // z0,z1,z2,fid
            float invz = w0 / q2.x + w1 / q2.y + w2 / q2.z;
            if (invz > INV_FAR_F) {
                float clz = fminf(fmaxf(invz, INV_FAR_F), INV_NEAR_F);
                float dep = 1.0f / clz;
                u64 cand = ((u64)__float_as_uint(dep) << 32) | (u64)__float_as_uint(q2.w);
                if (cand < best) { best = cand; bestd = __uint_as_float((u32)(best >> 32)); }
            }
        }
        __syncthreads();                          // protect LDS before next chunk
    }

    // exact merge of the 4 groups' partial (depth,fid) mins per pixel
    pb[l * 4 + g] = best;
    __syncthreads();

    // finalize inline: this block is the SOLE writer of its 64 pixels
    if (tid < 64) {
        u64 m = pb[tid * 4 + 0];
        u64 v1 = pb[tid * 4 + 1]; if (v1 < m) m = v1;
        u64 v2 = pb[tid * 4 + 2]; if (v2 < m) m = v2;
        u64 v3 = pb[tid * 4 + 3]; if (v3 < m) m = v3;

        const int fi = ir0 + (tid >> 3);
        const int fj = jc0 + (tid & 7);
        const int fp = fi * R_ + fj;
        float dep = __uint_as_float((u32)(m >> 32));
        float r = 0.0f, gg = 0.0f, bl = 0.0f, s = 0.0f;
        if (dep < HIT_THR_F) {
            int f = (int)(u32)m;
            s = 1.0f;
            float4 q0 = fq0[f], q1 = fq1[f], q2 = fq2[f];
            float fpx = pix_coord(fj);
            float fpy = -pix_coord(fi);
            float dx = fpx - q1.x, dy = fpy - q1.y;
            float w0 = (q0.x * dx + q0.y * dy) / q1.z;
            float w1 = (q0.z * dx + q0.w * dy) / q1.z;
            float w2 = 1.0f - w0 - w1;
            float wt0 = (w0 / q2.x) * dep;
            float wt1 = (w1 / q2.y) * dep;
            float wt2 = (w2 / q2.z) * dep;
            int t0 = (int)fminf(fmaxf(floorf(wt0 * 3.0f), 0.0f), 2.0f);
            int t1 = (int)fminf(fmaxf(floorf(wt1 * 3.0f), 0.0f), 2.0f);
            int t2 = (int)fminf(fmaxf(floorf(wt2 * 3.0f), 0.0f), 2.0f);
            int lin = f * 27 + t0 * 9 + t1 * 3 + t2;
            r  = tex[lin * 3 + 0];
            gg = tex[lin * 3 + 1];
            bl = tex[lin * 3 + 2];
        }
        out[0 * NPIX_ + fp] = r;
        out[1 * NPIX_ + fp] = gg;
        out[2 * NPIX_ + fp] = bl;
        out[3 * NPIX_ + fp] = s;
    }
}

// ---------------- fallback slice scan (ws too small; normally unused) ----------------
__global__ __launch_bounds__(256) void kscanS(const float4* __restrict__ fq0,
                                              const float4* __restrict__ fq1,
                                              const float4* __restrict__ fq2,
                                              const float4* __restrict__ bbx,
                                              const int* __restrict__ cull,
                                              u64* __restrict__ pd64)
{
#pragma clang fp contract(off)
    const int t = blockIdx.x, s = blockIdx.y;
    const int tid = threadIdx.x;
    const int ii = (t >> 3) * 16 + (tid >> 4);
    const int jj = (t & 7) * 16 + (tid & 15);
    const int p  = ii * R_ + jj;
    const float px = pix_coord(jj);
    const float py = -pix_coord(ii);
    const float tpx0 = pix_coord((t & 7) * 16), tpx1 = pix_coord((t & 7) * 16 + 15);
    const float tpy1 = -pix_coord((t >> 3) * 16), tpy0 = -pix_coord((t >> 3) * 16 + 15);
    const int f0 = s * FPS_, f1 = min(NF_, f0 + FPS_);

    u64 best = SENTINEL_ | 0xFFFFFFFFull;
    float bestd = 25.0f;

    for (int f = f0; f < f1; ++f) {
        if (cull[f]) continue;
        float4 bb = bbx[f];
        if (!(bb.x <= tpx1 && bb.y >= tpx0 && bb.z <= tpy1 && bb.w >= tpy0)) continue;
        float4 q1 = fq1[f];
        if (q1.w > bestd) continue;
        float4 q0 = fq0[f];
        float dx = px - q1.x, dy = py - q1.y;
        float n0 = q0.x * dx + q0.y * dy;
        float n1 = q0.z * dx + q0.w * dy;
        u32 sd = __float_as_uint(q1.z) >> 31;
        bool s0 = (n0 == 0.0f) || ((__float_as_uint(n0) >> 31) == sd);
        bool s1 = (n1 == 0.0f) || ((__float_as_uint(n1) >> 31) == sd);
        if (!(s0 && s1)) continue;
        float w0 = n0 / q1.z;
        float w1 = n1 / q1.z;
        float w2 = 1.0f - w0 - w1;
        if (!(w2 >= 0.0f)) continue;
        float4 q2 = fq2[f];
        float invz = w0 / q2.x + w1 / q2.y + w2 / q2.z;
        if (invz > INV_FAR_F) {
            float clz = fminf(fmaxf(invz, INV_FAR_F), INV_NEAR_F);
            float dep = 1.0f / clz;
            u64 cand = ((u64)__float_as_uint(dep) << 32) | (u64)__float_as_uint(q2.w);
            if (cand < best) { best = cand; bestd = __uint_as_float((u32)(best >> 32)); }
        }
    }
    if ((u32)best != 0xFFFFFFFFu) atomicMin(&pd64[p], best);
}

// ---------------- finalize (fallback path only) ----------------
__global__ __launch_bounds__(256) void kfin(const u64* __restrict__ pd64,
                                            const float4* __restrict__ fq0,
                                            const float4* __restrict__ fq1,
                                            const float4* __restrict__ fq2,
                                            const float* __restrict__ tex,
                                            float* __restrict__ out)
{
#pragma clang fp contract(off)
    int p = blockIdx.x * 256 + threadIdx.x;
    if (p >= NPIX_) return;
    int ii = p >> 7, jj = p & 127;

    u64 v = pd64[p];
    float dep = __uint_as_float((u32)(v >> 32));
    int f = (int)(u32)v;

    float r = 0.0f, g = 0.0f, bl = 0.0f, s = 0.0f;
    if (dep < HIT_THR_F) {
        s = 1.0f;
        float4 q0 = fq0[f], q1 = fq1[f], q2 = fq2[f];
        float px = pix_coord(jj);
        float py = -pix_coord(ii);
        float dx = px - q1.x, dy = py - q1.y;
        float w0 = (q0.x * dx + q0.y * dy) / q1.z;
        float w1 = (q0.z * dx + q0.w * dy) / q1.z;
        float w2 = 1.0f - w0 - w1;
        float wt0 = (w0 / q2.x) * dep;
        float wt1 = (w1 / q2.y) * dep;
        float wt2 = (w2 / q2.z) * dep;
        int t0 = (int)fminf(fmaxf(floorf(wt0 * 3.0f), 0.0f), 2.0f);
        int t1 = (int)fminf(fmaxf(floorf(wt1 * 3.0f), 0.0f), 2.0f);
        int t2 = (int)fminf(fmaxf(floorf(wt2 * 3.0f), 0.0f), 2.0f);
        int lin = f * 27 + t0 * 9 + t1 * 3 + t2;
        r  = tex[lin * 3 + 0];
        g  = tex[lin * 3 + 1];
        bl = tex[lin * 3 + 2];
    }
    out[0 * NPIX_ + p] = r;
    out[1 * NPIX_ + p] = g;
    out[2 * NPIX_ + p] = bl;
    out[3 * NPIX_ + p] = s;
}

extern "C" void kernel_launch(void* const* d_in, const int* in_sizes, int n_in,
                              void* d_out, int out_size, void* d_ws, size_t ws_size,
                              hipStream_t stream) {
    const float* verts = (const float*)d_in[0];
    const float* tex   = (const float*)d_in[1];
    const int*   faces = (const int*)d_in[2];
    float* out = (float*)d_out;

    char* ws = (char*)d_ws;
    size_t off = 0;
    u64*    pd64 = (u64*)   (ws + off); off += (size_t)NPIX_ * 8;   // fallback only
    u64*    tmask= (u64*)   (ws + off); off += (size_t)NF_ * 8;
    float4* fq0  = (float4*)(ws + off); off += (size_t)NF_ * 16;
    float4* fq1  = (float4*)(ws + off); off += (size_t)NF_ * 16;
    float4* fq2  = (float4*)(ws + off); off += (size_t)NF_ * 16;
    float4* bbx  = (float4*)(ws + off); off += (size_t)NF_ * 16;
    int*    cull = (int*)   (ws + off); off += (size_t)NF_ * 4;
    u32*    fw   = (u32*)   (ws + off); off += (size_t)NF_ * 4;
    int*    lenp = (int*)   (ws + off); off += 64 * 4;
    off = (off + 15) & ~(size_t)15;
    u32*    cnt  = (u32*)   (ws + off); off += (size_t)64 * NBKT_ * NSEG_ * 4;
    u32*    list = (u32*)   (ws + off);
    size_t need = off + (size_t)64 * NF_ * 4;
    int use_lists = (ws_size >= need) ? 1 : 0;

    const int FB = (NF_ + 255) / 256;            // 54
    if (use_lists) {
        kinit<<<64, 256, 0, stream>>>((uint4*)cnt);
        kpre <<<FB, 256, 0, stream>>>(verts, faces, fq0, fq1, fq2, bbx, cull,
                                      fw, tmask, cnt, 1);
        kbinsort2<<<64 * NSEG_, 256, 0, stream>>>(fw, tmask, cnt, list, lenp);
        kscan6<<<1024, 256, 0, stream>>>(fq0, fq1, fq2, lenp, list, tex, out);
    } else {
        kinitP<<<NPIX_ / 256, 256, 0, stream>>>(pd64);
        kpre <<<FB, 256, 0, stream>>>(verts, faces, fq0, fq1, fq2, bbx, cull,
                                      fw, tmask, cnt, 0);
        dim3 g(64, NSLICE_);
        kscanS<<<g, 256, 0, stream>>>(fq0, fq1, fq2, bbx, cull, pd64);
        kfin<<<NPIX_ / 256, 256, 0, stream>>>(pd64, fq0, fq1, fq2, tex, out);
    }
}

// Round 14
// 61.343 us; speedup vs baseline: 2.1587x; 2.1587x over previous
//
#include <hip/hip_runtime.h>
#include <math.h>
#include <stdint.h>

#define NF_     13776
#define R_      128
#define NPIX_   (R_ * R_)
#define CH_     256
#define NCHUNK_ ((NF_ + CH_ - 1) / CH_)          // 54
#define A_CH_   2
#define B_CH_   (NCHUNK_ - A_CH_)                // 52
#define NSLICE_ 32
#define FPS_    ((NF_ + NSLICE_ - 1) / NSLICE_)
#define NBKT_   256

typedef unsigned long long u64;
typedef unsigned int u32;

// exact f32 constants matching the JAX reference
#define EYEZ_F     (-2.7320508075688772935f)     // -(1/tan(30deg) + 1)
#define INV_FAR_F  (0.04f)
#define INV_NEAR_F (10.0f)
#define FAR_BITS   0x41C80000u                   // bits of 25.0f
#define HIT_THR_F  ((float)(25.0 * (1.0 - 1e-06)))
#define SENTINEL_  (((u64)FAR_BITS << 32))       // depth=FAR, fid=0
// z-bucket mapping: bucket = min(255, (int)(zeff*32)); BKT_LO(b) <= zmin_eff of all members
#define BKT_SCALE  32.0f
#define BKT_LO(b)  ((float)(b) * (0.03125f * 0.999999f))

static __device__ __forceinline__ float pix_coord(int j) {
    return (2.0f * (float)j + 1.0f - 128.0f) / 128.0f;   // exact in f32
}

static __device__ __forceinline__ void tile_masks(float4 bb, int& xm, int& ym) {
    xm = 0; ym = 0;
    #pragma unroll
    for (int t = 0; t < 8; ++t) {
        float tx0 = pix_coord(t * 16), tx1 = pix_coord(t * 16 + 15);
        if (bb.x <= tx1 && bb.y >= tx0) xm |= 1 << t;
        float ty1 = -pix_coord(t * 16), ty0 = -pix_coord(t * 16 + 15);
        if (bb.z <= ty1 && bb.w >= ty0) ym |= 1 << t;
    }
}

// Conservative: returns true => NO pixel center in [rx0,rx1]x[ry0,ry1] can pass
// the exact per-pixel sign tests s0&&s1. Linear edge fn attains extrema at rect
// corners; margin 1e-4 >> worst-case f32 rounding (~1e-5 at |terms|<=~40).
static __device__ __forceinline__ bool edge_cull(float a, float b, float c, float d,
                                                 float x2, float y2, float dets,
                                                 float rx0, float rx1,
                                                 float ry0, float ry1)
{
#pragma clang fp contract(off)
    float s = (__float_as_uint(dets) >> 31) ? -1.0f : 1.0f;
    float dx0 = rx0 - x2, dx1 = rx1 - x2;
    float dy0 = ry0 - y2, dy1 = ry1 - y2;
    float e0 = s * (a * dx0 + b * dy0);
    float e1 = s * (a * dx0 + b * dy1);
    float e2 = s * (a * dx1 + b * dy0);
    float e3 = s * (a * dx1 + b * dy1);
    if (fmaxf(fmaxf(e0, e1), fmaxf(e2, e3)) < -1e-4f) return true;
    float f0 = s * (c * dx0 + d * dy0);
    float f1 = s * (c * dx0 + d * dy1);
    float f2 = s * (c * dx1 + d * dy0);
    float f3 = s * (c * dx1 + d * dy1);
    return fmaxf(fmaxf(f0, f1), fmaxf(f2, f3)) < -1e-4f;
}

// ---- preprocess + edge-culled tile mask + pd64 sentinel init (no atomics) ----
__global__ __launch_bounds__(256) void kpre(const float* __restrict__ verts,
                                            const int* __restrict__ faces,
                                            float4* __restrict__ fq0,
                                            float4* __restrict__ fq1,
                                            float4* __restrict__ fq2,
                                            float4* __restrict__ bbx,
                                            int* __restrict__ cull,
                                            u32* __restrict__ fw,
                                            u64* __restrict__ tmask,
                                            u64* __restrict__ pd64)
{
#pragma clang fp contract(off)
    int idx = blockIdx.x * 256 + threadIdx.x;    // grid = 64 blocks = 16384 threads
    if (idx < NPIX_) pd64[idx] = SENTINEL_;      // depth buffer sentinel
    int f = idx;
    if (f >= NF_) return;
    int i0 = faces[3*f+0], i1 = faces[3*f+1], i2 = faces[3*f+2];
    float x0 = verts[3*i0+0], y0 = verts[3*i0+1], z0 = verts[3*i0+2] - EYEZ_F;
    float x1 = verts[3*i1+0], y1 = verts[3*i1+1], z1 = verts[3*i1+2] - EYEZ_F;
    float x2 = verts[3*i2+0], y2 = verts[3*i2+1], z2 = verts[3*i2+2] - EYEZ_F;

    float a = y1 - y2;
    float b = x2 - x1;
    float c = y2 - y0;
    float d = x0 - x2;
    float e = y0 - y2;
    float det = a * d + b * e;                   // no FMA (contract off)
    bool det_ok = fabsf(det) > 1e-10f;
    float dets = det_ok ? det : 1e-10f;
    bool zpos = (z0 > 0.1f) && (z1 > 0.1f) && (z2 > 0.1f);

    // conservative prune bound: any valid candidate's computed depth > zmin_eff (strict)
    float zmin_eff = fminf(z0, fminf(z1, z2)) * 0.99999f;

    float4 bb = make_float4(fminf(x0, fminf(x1, x2)) - 1e-4f,
                            fmaxf(x0, fmaxf(x1, x2)) + 1e-4f,
                            fminf(y0, fminf(y1, y2)) - 1e-4f,
                            fmaxf(y0, fmaxf(y1, y2)) + 1e-4f);
    int ok = (det_ok && zpos) ? 0 : 1;

    fq0[f] = make_float4(a, b, c, d);
    fq1[f] = make_float4(x2, y2, dets, zmin_eff);
    fq2[f] = make_float4(z0, z1, z2, __uint_as_float((u32)f));
    bbx[f] = bb;
    cull[f] = ok;

    u64 tm = 0;
    u32 w = 0;
    if (ok == 0) {
        int xm, ym; tile_masks(bb, xm, ym);
        u32 bkt = (u32)min(255, (int)(zmin_eff * BKT_SCALE));
        w = bkt << 16;
        for (int tr = 0; tr < 8; ++tr) if ((ym >> tr) & 1) {
            float ty1 = -pix_coord(tr * 16);         // max y in tile
            float ty0 = -pix_coord(tr * 16 + 15);    // min y in tile
            for (int tc = 0; tc < 8; ++tc) if ((xm >> tc) & 1) {
                float tx0 = pix_coord(tc * 16), tx1 = pix_coord(tc * 16 + 15);
                if (!edge_cull(a, b, c, d, x2, y2, dets, tx0, tx1, ty0, ty1))
                    tm |= 1ull << (tr * 8 + tc);
            }
        }
    }
    fw[f] = w;
    tmask[f] = tm;
}

// ---- per-tile count+prefix+scatter, 1024 threads, 4-deep prefetch both passes ----
__global__ __launch_bounds__(1024) void kbinsort(const u32* __restrict__ fw,
                                                 const u64* __restrict__ tmask,
                                                 u32* __restrict__ list,
                                                 int* __restrict__ len)
{
    __shared__ u32 lcnt[NBKT_];
    __shared__ u32 loff[NBKT_];
    const int t = blockIdx.x;
    const int tid = threadIdx.x;
    if (tid < NBKT_) lcnt[tid] = 0;
    __syncthreads();

    // count pass: unconditional prefetched loads (no dependent load->test->load chain)
    for (int base = 0; base < NF_; base += 4096) {
        u64 tm[4]; u32 w[4];
        #pragma unroll
        for (int u = 0; u < 4; ++u) {
            int f = base + u * 1024 + tid;
            tm[u] = (f < NF_) ? tmask[f] : 0ull;
        }
        #pragma unroll
        for (int u = 0; u < 4; ++u) {
            int f = base + u * 1024 + tid;
            w[u] = (f < NF_) ? fw[f] : 0u;
        }
        #pragma unroll
        for (int u = 0; u < 4; ++u)
            if ((tm[u] >> t) & 1ull)
                atomicAdd(&lcnt[w[u] >> 16], 1u);    // non-returning LDS atomic
    }
    __syncthreads();

    // exclusive prefix over 256 buckets (Hillis-Steele, first 256 threads)
    if (tid < NBKT_) loff[tid] = lcnt[tid];
    __syncthreads();
    for (int d = 1; d < NBKT_; d <<= 1) {
        u32 add = 0;
        if (tid < NBKT_ && tid >= d) add = loff[tid - d];
        __syncthreads();
        if (tid < NBKT_) loff[tid] += add;
        __syncthreads();
    }
    if (tid == NBKT_ - 1) len[t] = (int)loff[tid];
    u32 excl = 0;
    if (tid < NBKT_) excl = loff[tid] - lcnt[tid];
    __syncthreads();
    if (tid < NBKT_) loff[tid] = excl;               // exclusive starts
    __syncthreads();

    // scatter pass: same prefetch; within-bucket order arbitrary (safe: packed
    // (depth,fid) u64 argmin is fully order-independent); list bucket-ascending
    for (int base = 0; base < NF_; base += 4096) {
        u64 tm[4]; u32 w[4];
        #pragma unroll
        for (int u = 0; u < 4; ++u) {
            int f = base + u * 1024 + tid;
            tm[u] = (f < NF_) ? tmask[f] : 0ull;
        }
        #pragma unroll
        for (int u = 0; u < 4; ++u) {
            int f = base + u * 1024 + tid;
            w[u] = (f < NF_) ? fw[f] : 0u;
        }
        #pragma unroll
        for (int u = 0; u < 4; ++u) {
            if ((tm[u] >> t) & 1ull) {
                u32 bkt = w[u] >> 16;
                u32 slot = atomicAdd(&loff[bkt], 1u);
                list[(size_t)t * NF_ + slot] = (bkt << 16) | (u32)(base + u * 1024 + tid);
            }
        }
    }
}

// ------- scan: block = (tile, quadrant, chunk); 64 pixels x 4 candidate-groups -------
__global__ __launch_bounds__(256) void kscan5(const float4* __restrict__ fq0,
                                              const float4* __restrict__ fq1,
                                              const float4* __restrict__ fq2,
                                              const int* __restrict__ len,
                                              const u32* __restrict__ list,
                                              u64* __restrict__ pd64,
                                              int cbase)
{
#pragma clang fp contract(off)
    __shared__ float4 c0s[CH_], c1s[CH_], c2s[CH_];
    __shared__ u64 pb[256];
    const int bx = blockIdx.x;
    const int t = bx >> 2, q = bx & 3;               // tile, 8x8-px quadrant
    const int base = (cbase + (int)blockIdx.y) * CH_;
    const int len_t = len[t];
    if (base >= len_t) return;                       // uniform exit
    const int tid = threadIdx.x;
    const int g = tid >> 6, l = tid & 63;            // candidate-group (wave), pixel
    const int ir0 = (t >> 3) * 16 + (q >> 1) * 8;    // quadrant row base
    const int jc0 = (t & 7) * 16 + (q & 1) * 8;      // quadrant col base
    const int ii = ir0 + (l >> 3);
    const int jj = jc0 + (l & 7);
    const int p  = ii * R_ + jj;
    const float px = pix_coord(jj);
    const float py = -pix_coord(ii);
    const u32* lp = list + (size_t)t * NF_ + base;
    const int K = min(CH_, len_t - base);

    // monotone 4B read of current depth word: stale => larger => safe bound
    u32 seed = ((const volatile u32*)pd64)[2 * p + 1];
    float bestd = __uint_as_float(seed);
    u64 best = ((u64)seed << 32) | 0xFFFFFFFFull;

    // chunk prune: list ascending by bucket; BKT_LO lower-bounds every zmin_eff here.
    float blo = BKT_LO(lp[0] >> 16);
    if (__syncthreads_and(blo > bestd)) return;

    if (tid < K) {
        int f = (int)(lp[tid] & 0xFFFFu);
        float4 a0 = fq0[f];
        float4 a1 = fq1[f];
        // quadrant-level conservative edge cull: mark dead via zmin=+inf so the
        // normal per-candidate prune path skips it (bestd <= 25 < 1e30 always)
        if (edge_cull(a0.x, a0.y, a0.z, a0.w, a1.x, a1.y, a1.z,
                      pix_coord(jc0), pix_coord(jc0 + 7),
                      -pix_coord(ir0 + 7), -pix_coord(ir0)))
            a1.w = 1e30f;
        c0s[tid] = a0;
        c1s[tid] = a1;
        c2s[tid] = fq2[f];
    }
    __syncthreads();

    // interleaved split: group g takes k = g, g+4, ... (all groups sweep ascending z)
    for (int k = g; k < K; k += 4) {
        float4 q1 = c1s[k];                   // x2,y2,det,zmin_eff (LDS broadcast)
        if (q1.w > bestd) continue;           // strict: preserves exact ties
        float4 q0 = c0s[k];                   // a,b,c,d
        float dx = px - q1.x, dy = py - q1.y;
        float n0 = q0.x * dx + q0.y * dy;
        float n1 = q0.z * dx + q0.w * dy;
        u32 sd = __float_as_uint(q1.z) >> 31;
        bool s0 = (n0 == 0.0f) || ((__float_as_uint(n0) >> 31) == sd);
        bool s1 = (n1 == 0.0f) || ((__float_as_uint(n1) >> 31) == sd);
        if (!(s0 && s1)) continue;
        float w0 = n0 / q1.z;
        float w1 = n1 / q1.z;
        float w2 = 1.0f - w0 - w1;
        if (!(w2 >= 0.0f)) continue;
        float4 q2 = c2s[k];                   // z0,z1,z2,fid
        float invz = w0 / q2.x + w1 / q2.y + w2 / q2.z;
        if (invz > INV_FAR_F) {
            float clz = fminf(fmaxf(invz, INV_FAR_F), INV_NEAR_F);
            float dep = 1.0f / clz;
            u64 cand = ((u64)__float_as_uint(dep) << 32) | (u64)__float_as_uint(q2.w);
            if (cand < best) { best = cand; bestd = __uint_as_float((u32)(best >> 32)); }
        }
    }

    // exact merge of 4 partial (depth,fid) mins per pixel
    pb[l * 4 + g] = best;
    __syncthreads();
    if (tid < 64) {
        u64 m = pb[tid * 4 + 0];
        u64 v1 = pb[tid * 4 + 1]; if (v1 < m) m = v1;
        u64 v2 = pb[tid * 4 + 2]; if (v2 < m) m = v2;
        u64 v3 = pb[tid * 4 + 3]; if (v3 < m) m = v3;
        if ((u32)m != 0xFFFFFFFFu) atomicMin(&pd64[p], m);
    }
}

// ---------------- fallback slice scan (ws too small; normally unused) ----------------
__global__ __launch_bounds__(256) void kscanS(const float4* __restrict__ fq0,
                                              const float4* __restrict__ fq1,
                                              const float4* __restrict__ fq2,
                                              const float4* __restrict__ bbx,
                                              const int* __restrict__ cull,
                                              u64* __restrict__ pd64)
{
#pragma clang fp contract(off)
    const int t = blockIdx.x, s = blockIdx.y;
    const int tid = threadIdx.x;
    const int ii = (t >> 3) * 16 + (tid >> 4);
    const int jj = (t & 7) * 16 + (tid & 15);
    const int p  = ii * R_ + jj;
    const float px = pix_coord(jj);
    const float py = -pix_coord(ii);
    const float tpx0 = pix_coord((t & 7) * 16), tpx1 = pix_coord((t & 7) * 16 + 15);
    const float tpy1 = -pix_coord((t >> 3) * 16), tpy0 = -pix_coord((t >> 3) * 16 + 15);
    const int f0 = s * FPS_, f1 = min(NF_, f0 + FPS_);

    u64 best = SENTINEL_ | 0xFFFFFFFFull;
    float bestd = 25.0f;

    for (int f = f0; f < f1; ++f) {
        if (cull[f]) continue;
        float4 bb = bbx[f];
        if (!(bb.x <= tpx1 && bb.y >= tpx0 && bb.z <= tpy1 && bb.w >= tpy0)) continue;
        float4 q1 = fq1[f];
        if (q1.w > bestd) continue;
        float4 q0 = fq0[f];
        float dx = px - q1.x, dy = py - q1.y;
        float n0 = q0.x * dx + q0.y * dy;
        float n1 = q0.z * dx + q0.w * dy;
        u32 sd = __float_as_uint(q1.z) >> 31;
        bool s0 = (n0 == 0.0f) || ((__float_as_uint(n0) >> 31) == sd);
        bool s1 = (n1 == 0.0f) || ((__float_as_uint(n1) >> 31) == sd);
        if (!(s0 && s1)) continue;
        float w0 = n0 / q1.z;
        float w1 = n1 / q1.z;
        float w2 = 1.0f - w0 - w1;
        if (!(w2 >= 0.0f)) continue;
        float4 q2 = fq2[f];
        float invz = w0 / q2.x + w1 / q2.y + w2 / q2.z;
        if (invz > INV_FAR_F) {
            float clz = fminf(fmaxf(invz, INV_FAR_F), INV_NEAR_F);
            float dep = 1.0f / clz;
            u64 cand = ((u64)__float_as_uint(dep) << 32) | (u64)__float_as_uint(q2.w);
            if (cand < best) { best = cand; bestd = __uint_as_float((u32)(best >> 32)); }
        }
    }
    if ((u32)best != 0xFFFFFFFFu) atomicMin(&pd64[p], best);
}

// ---------------- finalize ----------------
__global__ __launch_bounds__(256) void kfin(const u64* __restrict__ pd64,
                                            const float4* __restrict__ fq0,
                                            const float4* __restrict__ fq1,
                                            const float4* __restrict__ fq2,
                                            const float* __restrict__ tex,
                                            float* __restrict__ out)
{
#pragma clang fp contract(off)
    int p = blockIdx.x * 256 + threadIdx.x;
    if (p >= NPIX_) return;
    int ii = p >> 7, jj = p & 127;

    u64 v = pd64[p];
    float dep = __uint_as_float((u32)(v >> 32));
    int f = (int)(u32)v;

    float r = 0.0f, g = 0.0f, bl = 0.0f, s = 0.0f;
    if (dep < HIT_THR_F) {
        s = 1.0f;
        float4 q0 = fq0[f], q1 = fq1[f], q2 = fq2[f];
        float px = pix_coord(jj);
        float py = -pix_coord(ii);
        float dx = px - q1.x, dy = py - q1.y;
        float w0 = (q0.x * dx + q0.y * dy) / q1.z;
        float w1 = (q0.z * dx + q0.w * dy) / q1.z;
        float w2 = 1.0f - w0 - w1;
        float wt0 = (w0 / q2.x) * dep;
        float wt1 = (w1 / q2.y) * dep;
        float wt2 = (w2 / q2.z) * dep;
        int t0 = (int)fminf(fmaxf(floorf(wt0 * 3.0f), 0.0f), 2.0f);
        int t1 = (int)fminf(fmaxf(floorf(wt1 * 3.0f), 0.0f), 2.0f);
        int t2 = (int)fminf(fmaxf(floorf(wt2 * 3.0f), 0.0f), 2.0f);
        int lin = f * 27 + t0 * 9 + t1 * 3 + t2;
        r  = tex[lin * 3 + 0];
        g  = tex[lin * 3 + 1];
        bl = tex[lin * 3 + 2];
    }
    out[0 * NPIX_ + p] = r;
    out[1 * NPIX_ + p] = g;
    out[2 * NPIX_ + p] = bl;
    out[3 * NPIX_ + p] = s;
}

extern "C" void kernel_launch(void* const* d_in, const int* in_sizes, int n_in,
                              void* d_out, int out_size, void* d_ws, size_t ws_size,
                              hipStream_t stream) {
    const float* verts = (const float*)d_in[0];
    const float* tex   = (const float*)d_in[1];
    const int*   faces = (const int*)d_in[2];
    float* out = (float*)d_out;

    char* ws = (char*)d_ws;
    size_t off = 0;
    u64*    pd64 = (u64*)   (ws + off); off += (size_t)NPIX_ * 8;
    u64*    tmask= (u64*)   (ws + off); off += (size_t)NF_ * 8;
    float4* fq0  = (float4*)(ws + off); off += (size_t)NF_ * 16;
    float4* fq1  = (float4*)(ws + off); off += (size_t)NF_ * 16;
    float4* fq2  = (float4*)(ws + off); off += (size_t)NF_ * 16;
    float4* bbx  = (float4*)(ws + off); off += (size_t)NF_ * 16;
    int*    cull = (int*)   (ws + off); off += (size_t)NF_ * 4;
    u32*    fw   = (u32*)   (ws + off); off += (size_t)NF_ * 4;
    int*    lenp = (int*)   (ws + off); off += 64 * 4;
    off = (off + 15) & ~(size_t)15;
    u32*    list = (u32*)   (ws + off);
    size_t need = off + (size_t)64 * NF_ * 4;
    int use_lists = (ws_size >= need) ? 1 : 0;

    // grid 64 blocks: threads cover NPIX_ for pd64 init AND NF_ for faces
    kpre<<<NPIX_ / 256, 256, 0, stream>>>(verts, faces, fq0, fq1, fq2, bbx, cull,
                                          fw, tmask, pd64);
    if (use_lists) {
        kbinsort<<<64, 1024, 0, stream>>>(fw, tmask, list, lenp);
        dim3 gA(256, A_CH_);
        kscan5<<<gA, 256, 0, stream>>>(fq0, fq1, fq2, lenp, list, pd64, 0);
        dim3 gB(256, B_CH_);
        kscan5<<<gB, 256, 0, stream>>>(fq0, fq1, fq2, lenp, list, pd64, A_CH_);
    } else {
        dim3 g(64, NSLICE_);
        kscanS<<<g, 256, 0, stream>>>(fq0, fq1, fq2, bbx, cull, pd64);
    }
    kfin<<<NPIX_ / 256, 256, 0, stream>>>(pd64, fq0, fq1, fq2, tex, out);
}